// Round 9
// baseline (328.642 us; speedup 1.0000x reference)
//
#include <hip/hip_runtime.h>
#include <hip/hip_bf16.h>
#include <math.h>

#define DPOS 768
#define ROWS 8192           // 32*256
#define NEG_INF_V (-10000.0f)
#define NSPLIT 16

// ---- 8-phase pipelined 256^2 geometry for k_lse8p ----
#define BM 256
#define BN 256
#define BK 64
#define CPS (ROWS / NSPLIT)   // cols per split = 512
#define NCT (CPS / BN)        // col-tiles per block = 2
#define NKT (DPOS / BK)       // K-tiles per col-tile = 12
#define GTOT (NCT * NKT)      // 24
#define TITER (GTOT / 2)      // 12 iterations (2 K-tiles each)
#define KWRAP (NKT * 128)     // 1536 bytes of K per row
#define CADV (BN * DPOS * 2)  // 393216 bytes per col-tile advance

typedef __attribute__((ext_vector_type(8))) __bf16 bf16x8;
typedef __attribute__((ext_vector_type(4))) __bf16 bf16x4;
typedef __attribute__((ext_vector_type(4))) float f32x4;

typedef const __attribute__((address_space(1))) unsigned int* gptr_t;
typedef __attribute__((address_space(3))) unsigned int* lptr_t;

#define SBAR() __builtin_amdgcn_s_barrier()
#define VMW(N) asm volatile("s_waitcnt vmcnt(" #N ")" ::: "memory")

// ---------------- fp32 -> bf16 conversion (two arrays per launch) ----------------
__global__ __launch_bounds__(256) void k_f2bf2(const float* __restrict__ a,
                                               const float* __restrict__ b,
                                               __bf16* __restrict__ da,
                                               __bf16* __restrict__ db, int n) {
    int i = (blockIdx.x * blockDim.x + threadIdx.x) * 4;
    const float* s = (i < n) ? a : b;
    __bf16* d = (i < n) ? da : db;
    int j = (i < n) ? i : i - n;
    float4 v = *(const float4*)(s + j);
    bf16x4 o = {(__bf16)v.x, (__bf16)v.y, (__bf16)v.z, (__bf16)v.w};
    *(bf16x4*)(d + j) = o;
}

// ---------------- LDS-staged GEMM C = A * B^T (+bias, epilogue), bf16 out ----------
template <int MODE>
__global__ __launch_bounds__(256, 3) void k_gemm_ld(const __bf16* __restrict__ A,
                                                    const __bf16* __restrict__ B,
                                                    const float* __restrict__ bias,
                                                    __bf16* __restrict__ outB) {
    __shared__ __align__(16) char sAB[32768];   // A[128][64]@0, B[128][64]@16384

    const int tid = threadIdx.x;
    const int lane = tid & 63;
    const int wave = tid >> 6;
    const int wr = wave >> 1, wc = wave & 1;
    const int lr = lane & 15;
    const int lk = (lane >> 4) * 8;
    const int rr = (lane >> 4) * 4;
    const int row0 = blockIdx.x * 128;
    const int col0 = blockIdx.y * 128;

    int o[4];
    const char* As[4];
    const char* Bs[4];
#pragma unroll
    for (int c = 0; c < 4; ++c) {
        int off = tid * 16 + c * 4096;
        int row = off >> 7;
        int scol = (off & 127) ^ ((row & 7) << 4);
        o[c] = off;
        As[c] = (const char*)A + ((size_t)(row0 + row)) * (DPOS * 2) + scol;
        Bs[c] = (const char*)B + ((size_t)(col0 + row)) * (DPOS * 2) + scol;
    }

    const int sws = (lr & 7) << 4;
    const int colK0 = (lk * 2) ^ sws;
    const int colK1 = (lk * 2 + 64) ^ sws;
    const int aB0 = (wr * 64 + lr) * 128 + colK0, aB1 = (wr * 64 + lr) * 128 + colK1;
    const int bB0 = 16384 + (wc * 64 + lr) * 128 + colK0;
    const int bB1 = 16384 + (wc * 64 + lr) * 128 + colK1;

    f32x4 acc[4][4];
#pragma unroll
    for (int i = 0; i < 4; ++i)
#pragma unroll
        for (int j = 0; j < 4; ++j) acc[i][j] = (f32x4){0.f, 0.f, 0.f, 0.f};

#pragma unroll 1
    for (int kc = 0; kc < DPOS / BK; ++kc) {
        const int kb = kc * (BK * 2);
#pragma unroll
        for (int c = 0; c < 4; ++c) {
            __builtin_amdgcn_global_load_lds((gptr_t)(As[c] + kb),
                                             (lptr_t)(sAB + o[c]), 16, 0, 0);
            __builtin_amdgcn_global_load_lds((gptr_t)(Bs[c] + kb),
                                             (lptr_t)(sAB + 16384 + o[c]), 16, 0, 0);
        }
        __syncthreads();
#pragma unroll
        for (int kk = 0; kk < 2; ++kk) {
            const int aBase = kk ? aB1 : aB0;
            const int bBase = kk ? bB1 : bB0;
            bf16x8 af[4], bf_[4];
#pragma unroll
            for (int mi = 0; mi < 4; ++mi)
                af[mi] = *(const bf16x8*)(sAB + aBase + mi * 2048);
#pragma unroll
            for (int ni = 0; ni < 4; ++ni)
                bf_[ni] = *(const bf16x8*)(sAB + bBase + ni * 2048);
#pragma unroll
            for (int i = 0; i < 4; ++i)
#pragma unroll
                for (int j = 0; j < 4; ++j)
                    acc[i][j] = __builtin_amdgcn_mfma_f32_16x16x32_bf16(
                        af[i], bf_[j], acc[i][j], 0, 0, 0);
        }
        __syncthreads();
    }

#pragma unroll
    for (int j = 0; j < 4; ++j) {
        int col = col0 + wc * 64 + j * 16 + lr;
        float bv = bias[col];
#pragma unroll
        for (int i = 0; i < 4; ++i)
#pragma unroll
            for (int v = 0; v < 4; ++v) {
                int row = row0 + wr * 64 + i * 16 + rr + v;
                float val = acc[i][j][v] + bv;
                if (MODE == 0)
                    val = 0.5f * val * (1.0f + erff(val * 0.70710678118654752f));
                outB[(size_t)row * DPOS + col] = (__bf16)val;
            }
    }
}

// ---------------- LayerNorm over last dim (768), one block per row, bf16 in/out ----------------
__global__ __launch_bounds__(256) void k_ln(const __bf16* __restrict__ h,
                                            const float* __restrict__ g,
                                            const float* __restrict__ bta,
                                            __bf16* __restrict__ out) {
    int row = blockIdx.x;
    const __bf16* hr = h + (size_t)row * DPOS;
    float v[3], s = 0.f, sq = 0.f;
#pragma unroll
    for (int t = 0; t < 3; ++t) {
        v[t] = (float)hr[threadIdx.x + t * 256];
        s += v[t];
        sq += v[t] * v[t];
    }
#pragma unroll
    for (int m = 32; m >= 1; m >>= 1) {
        s += __shfl_xor(s, m);
        sq += __shfl_xor(sq, m);
    }
    __shared__ float ss[4], sqq[4];
    int wave = threadIdx.x >> 6, lane = threadIdx.x & 63;
    if (lane == 0) { ss[wave] = s; sqq[wave] = sq; }
    __syncthreads();
    s = ss[0] + ss[1] + ss[2] + ss[3];
    sq = sqq[0] + sqq[1] + sqq[2] + sqq[3];
    float mu = s * (1.0f / DPOS);
    float var = sq * (1.0f / DPOS) - mu * mu;
    float r = rsqrtf(var + 1e-12f);
#pragma unroll
    for (int t = 0; t < 3; ++t) {
        int c = threadIdx.x + t * 256;
        out[(size_t)row * DPOS + c] = (__bf16)((v[t] - mu) * r * g[c] + bta[c]);
    }
}

// ======== fused logits + logsumexp: 8-phase, ONE-PHASE-LOOKAHEAD pipelined reads ======
// 512 thr / 8 waves (2wr x 4wc), per-wave C = 128x64. LDS: 2 slots x 64KB
// (A[256][64]@0, B[256][64]@32768 per slot). Phase p: MFMA consumes fragments
// read in phase p-1; phase p's ds_reads (next quadrant A / next K-tile B) fly
// DURING the MFMA (compiler's dependence-tracked lgkmcnt keeps them uncounted).
// Stage schedule (per iter i, K-tiles g=2i [s0], g+1 [s1]):
//   ph1: s1-Alo(g+1)  ph2: s1-Ahi(g+1)  ph4: s0-B(g+2)  ph5: s0-Alo(g+2)
//   ph6: s0-Ahi(g+2)  ph8: s1-B(g+3)
// VMW(4) at ph3/ph4/ph7/ph8 releases exactly the half-tiles the next ds_read needs.
__global__ __launch_bounds__(512, 1) void k_lse8p(const __bf16* __restrict__ E,
                                                  const __bf16* __restrict__ L,
                                                  const float* __restrict__ vm,
                                                  float* __restrict__ pm,
                                                  float* __restrict__ ps) {
    extern __shared__ char sAB[];
    __shared__ float svm[CPS];
    __shared__ float smm[2][4][128], sms[2][4][128];

    const int tid = threadIdx.x;
    const int lane = tid & 63;
    const int wave = tid >> 6;
    const int wr = wave >> 2, wc = wave & 3;
    const int lr = lane & 15;
    const int lk = (lane >> 4) * 8;
    const int rr = (lane >> 4) * 4;
    const int split = blockIdx.y;
    const int row0 = blockIdx.x * BM;

    svm[tid] = vm[split * CPS + tid];   // CPS == 512 == blockDim

    unsigned mrow = 0;
#pragma unroll
    for (int mi = 0; mi < 8; ++mi) {
        float4 mv = *(const float4*)(vm + row0 + wr * 128 + mi * 16 + rr);
        if (mv.x != 0.f) mrow |= 1u << (mi * 4 + 0);
        if (mv.y != 0.f) mrow |= 1u << (mi * 4 + 1);
        if (mv.z != 0.f) mrow |= 1u << (mi * 4 + 2);
        if (mv.w != 0.f) mrow |= 1u << (mi * 4 + 3);
    }

    // staging geometry: region 32KB per operand; c=0,1 -> rows 0-127 (lo), c=2,3 -> hi
    int o[4];
    const char* EsA[4];
    const char* LsB[4];
#pragma unroll
    for (int c = 0; c < 4; ++c) {
        int off = tid * 16 + c * 8192;
        int row = off >> 7;                        // 0..255
        int scol = (off & 127) ^ ((row & 7) << 4);
        o[c] = off;
        EsA[c] = (const char*)E + ((size_t)(row0 + row)) * (DPOS * 2) + scol;
        LsB[c] = (const char*)L + ((size_t)(split * CPS + row)) * (DPOS * 2) + scol;
    }

#define SA01(SLOT, KB) do { \
    __builtin_amdgcn_global_load_lds((gptr_t)(EsA[0] + (KB)), (lptr_t)(sAB + (SLOT) * 65536 + o[0]), 16, 0, 0); \
    __builtin_amdgcn_global_load_lds((gptr_t)(EsA[1] + (KB)), (lptr_t)(sAB + (SLOT) * 65536 + o[1]), 16, 0, 0); \
} while (0)
#define SA23(SLOT, KB) do { \
    __builtin_amdgcn_global_load_lds((gptr_t)(EsA[2] + (KB)), (lptr_t)(sAB + (SLOT) * 65536 + o[2]), 16, 0, 0); \
    __builtin_amdgcn_global_load_lds((gptr_t)(EsA[3] + (KB)), (lptr_t)(sAB + (SLOT) * 65536 + o[3]), 16, 0, 0); \
} while (0)
#define SB4(SLOT, KB, CRB) do { \
    __builtin_amdgcn_global_load_lds((gptr_t)(LsB[0] + (KB) + (CRB)), (lptr_t)(sAB + (SLOT) * 65536 + 32768 + o[0]), 16, 0, 0); \
    __builtin_amdgcn_global_load_lds((gptr_t)(LsB[1] + (KB) + (CRB)), (lptr_t)(sAB + (SLOT) * 65536 + 32768 + o[1]), 16, 0, 0); \
    __builtin_amdgcn_global_load_lds((gptr_t)(LsB[2] + (KB) + (CRB)), (lptr_t)(sAB + (SLOT) * 65536 + 32768 + o[2]), 16, 0, 0); \
    __builtin_amdgcn_global_load_lds((gptr_t)(LsB[3] + (KB) + (CRB)), (lptr_t)(sAB + (SLOT) * 65536 + 32768 + o[3]), 16, 0, 0); \
} while (0)

    // ds_read lane-constant bases
    const int sws = (lr & 7) << 4;
    const int colK0 = (lk * 2) ^ sws;
    const int colK1 = (lk * 2 + 64) ^ sws;
    const int aOff0 = (wr * 128 + lr) * 128 + colK0;
    const int aOff1 = (wr * 128 + lr) * 128 + colK1;
    const int bOff0 = 32768 + (wc * 64 + lr) * 128 + colK0;
    const int bOff1 = 32768 + (wc * 64 + lr) * 128 + colK1;

    // A-quadrant read: 2 mi x 2 kk fragments (quadrant QR = rows QR*32..QR*32+31 of wave)
#define RDA(DST, SLOT, QR) do { \
    _Pragma("unroll") \
    for (int mi = 0; mi < 2; ++mi) { \
        DST[mi][0] = *(const bf16x8*)(sAB + (SLOT) * 65536 + ((QR) * 32 + mi * 16) * 128 + aOff0); \
        DST[mi][1] = *(const bf16x8*)(sAB + (SLOT) * 65536 + ((QR) * 32 + mi * 16) * 128 + aOff1); \
    } \
} while (0)
#define RDB(DST, SLOT) do { \
    _Pragma("unroll") \
    for (int ni = 0; ni < 4; ++ni) { \
        DST[ni][0] = *(const bf16x8*)(sAB + (SLOT) * 65536 + ni * 2048 + bOff0); \
        DST[ni][1] = *(const bf16x8*)(sAB + (SLOT) * 65536 + ni * 2048 + bOff1); \
    } \
} while (0)

#define MFMAQ(Q, A, B) do { \
    __builtin_amdgcn_s_setprio(1); \
    _Pragma("unroll") \
    for (int mi = 0; mi < 2; ++mi) \
        _Pragma("unroll") \
        for (int ni = 0; ni < 4; ++ni) \
            _Pragma("unroll") \
            for (int kk = 0; kk < 2; ++kk) \
                acc[(Q) * 2 + mi][ni] = __builtin_amdgcn_mfma_f32_16x16x32_bf16( \
                    A[mi][kk], B[ni][kk], acc[(Q) * 2 + mi][ni], 0, 0, 0); \
    __builtin_amdgcn_s_setprio(0); \
} while (0)

    bf16x8 aE[2][2], aO[2][2], bX[4][2], bY[4][2];
    f32x4 acc[8][4];
#pragma unroll
    for (int mi = 0; mi < 8; ++mi)
#pragma unroll
        for (int ni = 0; ni < 4; ++ni) acc[mi][ni] = (f32x4){0.f, 0.f, 0.f, 0.f};

    float Mrun = -1e30f, Srun = 0.f;

    // ---- prologue: s0 full (g0), s1-B (g1); drain; pre-read A(g0,q0)+B(g0) ----
    SA01(0, 0); SA23(0, 0); SB4(0, 0, 0);
    SB4(1, 128, 0);
    VMW(0);
    SBAR();
    RDA(aE, 0, 0);
    RDB(bX, 0);
    SBAR();

    int kb1 = 128;                   // st1: s1-A, K-tile 2i+1
    int kbA = 256, crbA = 0;         // st2: s0 A+B, K-tile 2i+2
    int kbB = 384, crbB = 0;         // st3: s1-B, K-tile 2i+3

#pragma unroll 1
    for (int i = 0; i < TITER; ++i) {
        const bool nt = (i + 1 < TITER);

        // ph1: MFMA (g,q0)
        SA01(1, kb1);
        RDA(aO, 0, 1);
        SBAR(); MFMAQ(0, aE, bX); SBAR();
        // ph2: MFMA (g,q1)
        SA23(1, kb1);
        RDA(aE, 0, 2);
        SBAR(); MFMAQ(1, aO, bX); SBAR();
        // ph3: MFMA (g,q2); read B(g+1) from s1
        VMW(4);
        RDA(aO, 0, 3);
        RDB(bY, 1);
        SBAR(); MFMAQ(2, aE, bX); SBAR();
        // ph4: MFMA (g,q3); read A(g+1,q0) from s1
        if (nt) SB4(0, kbA, crbA);
        VMW(4);
        RDA(aE, 1, 0);
        SBAR(); MFMAQ(3, aO, bX); SBAR();
        // ph5: MFMA (g+1,q0)
        if (nt) SA01(0, kbA);
        RDA(aO, 1, 1);
        SBAR(); MFMAQ(0, aE, bY); SBAR();
        // ph6: MFMA (g+1,q1)
        if (nt) SA23(0, kbA);
        RDA(aE, 1, 2);
        SBAR(); MFMAQ(1, aO, bY); SBAR();
        // ph7: MFMA (g+1,q2); read B(g+2) from s0
        VMW(4);
        RDA(aO, 1, 3);
        RDB(bX, 0);
        SBAR(); MFMAQ(2, aE, bY); SBAR();
        // ph8: MFMA (g+1,q3); read A(g+2,q0) from s0
        if (nt) SB4(1, kbB, crbB);
        VMW(4);
        RDA(aE, 0, 0);
        SBAR(); MFMAQ(3, aO, bY); SBAR();

        kb1 += 256; if (kb1 >= KWRAP) kb1 -= KWRAP;
        kbA += 256; if (kbA >= KWRAP) { kbA -= KWRAP; crbA += CADV; }
        kbB += 256; if (kbB >= KWRAP) { kbB -= KWRAP; crbB += CADV; }

        // ---- col-tile epilogue (i % 6 == 5): online softmax over 256x256 tile ----
        if ((i % (NKT / 2)) == (NKT / 2 - 1)) {
            const int ct = i / (NKT / 2);
            float cmv[4];
#pragma unroll
            for (int ni = 0; ni < 4; ++ni) cmv[ni] = svm[ct * BN + wc * 64 + ni * 16 + lr];
#pragma unroll
            for (int mi = 0; mi < 8; ++mi) {
#pragma unroll
                for (int v = 0; v < 4; ++v) {
                    bool rv = (mrow >> (mi * 4 + v)) & 1u;
                    float x0 = acc[mi][0][v] + ((rv && cmv[0] == 0.f) ? NEG_INF_V : 0.f);
                    float x1 = acc[mi][1][v] + ((rv && cmv[1] == 0.f) ? NEG_INF_V : 0.f);
                    float x2 = acc[mi][2][v] + ((rv && cmv[2] == 0.f) ? NEG_INF_V : 0.f);
                    float x3 = acc[mi][3][v] + ((rv && cmv[3] == 0.f) ? NEG_INF_V : 0.f);
                    float m4 = fmaxf(fmaxf(x0, x1), fmaxf(x2, x3));
                    float s4 = __expf(x0 - m4) + __expf(x1 - m4) +
                               __expf(x2 - m4) + __expf(x3 - m4);
#pragma unroll
                    for (int d = 1; d < 16; d <<= 1) {
                        float mo = __shfl_xor(m4, d);
                        float so = __shfl_xor(s4, d);
                        float nm = fmaxf(m4, mo);
                        s4 = s4 * __expf(m4 - nm) + so * __expf(mo - nm);
                        m4 = nm;
                    }
                    if (lr == 0) {
                        smm[wr][wc][mi * 16 + rr + v] = m4;
                        sms[wr][wc][mi * 16 + rr + v] = s4;
                    }
                }
#pragma unroll
                for (int ni = 0; ni < 4; ++ni) acc[mi][ni] = (f32x4){0.f, 0.f, 0.f, 0.f};
            }
            __syncthreads();
            if (tid < 256) {
                int rl = tid & 127, wrh = tid >> 7;
                float m = smm[wrh][0][rl], s = sms[wrh][0][rl];
#pragma unroll
                for (int w = 1; w < 4; ++w) {
                    float mo = smm[wrh][w][rl], so = sms[wrh][w][rl];
                    float nm = fmaxf(m, mo);
                    s = s * __expf(m - nm) + so * __expf(mo - nm);
                    m = nm;
                }
                float nm = fmaxf(Mrun, m);
                Srun = Srun * __expf(Mrun - nm) + s * __expf(m - nm);
                Mrun = nm;
            }
            __syncthreads();
        }
    }
#undef MFMAQ
#undef RDA
#undef RDB
#undef SA01
#undef SA23
#undef SB4

    if (tid < 256) {
        int rl = tid & 127, wrh = tid >> 7;
        size_t idx = (size_t)(row0 + wrh * 128 + rl) * NSPLIT + split;
        pm[idx] = Mrun;
        ps[idx] = Srun;
    }
}

// ---------------- diagonal: diag[i] = dot(emb_i, labels_i) ----------------
__global__ __launch_bounds__(256) void k_diag(const __bf16* __restrict__ E,
                                              const __bf16* __restrict__ L,
                                              float* __restrict__ diag) {
    int wave = threadIdx.x >> 6, lane = threadIdx.x & 63;
    int row = blockIdx.x * 4 + wave;
    const __bf16* e = E + (size_t)row * DPOS;
    const __bf16* l = L + (size_t)row * DPOS;
    float s = 0.f;
    for (int k = lane * 8; k < DPOS; k += 64 * 8) {
        bf16x8 a = *(const bf16x8*)(e + k);
        bf16x8 b = *(const bf16x8*)(l + k);
#pragma unroll
        for (int j = 0; j < 8; ++j) s += (float)a[j] * (float)b[j];
    }
#pragma unroll
    for (int m = 32; m >= 1; m >>= 1) s += __shfl_xor(s, m);
    if (lane == 0) diag[row] = s;
}

// ---------------- combine partials + masked mean ----------------
__global__ __launch_bounds__(256) void k_loss(const float* __restrict__ pm,
                                              const float* __restrict__ ps,
                                              const float* __restrict__ diag,
                                              const int* __restrict__ idx,
                                              float* __restrict__ out) {
    float accn = 0.f, accd = 0.f;
    for (int i = threadIdx.x; i < ROWS; i += 256) {
        float m = pm[i * NSPLIT + 0], s = ps[i * NSPLIT + 0];
#pragma unroll
        for (int c = 1; c < NSPLIT; ++c) {
            float mo = pm[i * NSPLIT + c], so = ps[i * NSPLIT + c];
            float nm = fmaxf(m, mo);
            s = s * __expf(m - nm) + so * __expf(mo - nm);
            m = nm;
        }
        float lse = m + logf(s);
        bool valid = (idx[i] != -100);
        if (valid) {
            accn += diag[i] - lse;
            accd += 1.f;
        }
    }
#pragma unroll
    for (int m = 32; m >= 1; m >>= 1) {
        accn += __shfl_xor(accn, m);
        accd += __shfl_xor(accd, m);
    }
    __shared__ float an[4], ad[4];
    int wave = threadIdx.x >> 6, lane = threadIdx.x & 63;
    if (lane == 0) { an[wave] = accn; ad[wave] = accd; }
    __syncthreads();
    if (threadIdx.x == 0) {
        float n = an[0] + an[1] + an[2] + an[3];
        float d = ad[0] + ad[1] + ad[2] + ad[3];
        out[0] = -n / d;
    }
}

extern "C" void kernel_launch(void* const* d_in, const int* in_sizes, int n_in,
                              void* d_out, int out_size, void* d_ws, size_t ws_size,
                              hipStream_t stream) {
    const float* x      = (const float*)d_in[0];   // [8192][768]
    const float* labels = (const float*)d_in[1];   // [8192][768]
    const int*   lidx   = (const int*)d_in[2];     // [8192]
    const float* vm     = (const float*)d_in[3];   // [8192]
    const float* W1     = (const float*)d_in[4];   // [768][768]
    const float* b1     = (const float*)d_in[5];
    const float* ln_g   = (const float*)d_in[6];
    const float* ln_b   = (const float*)d_in[7];
    const float* Wd     = (const float*)d_in[8];
    const float* b_dec  = (const float*)d_in[9];
    float* out = (float*)d_out;

    const size_t NE = (size_t)ROWS * DPOS;       // 6291456
    const size_t NW = (size_t)DPOS * DPOS;       // 589824
    char* p = (char*)d_ws;
    __bf16* xb   = (__bf16*)p;            p += NE * 2;
    __bf16* labb = (__bf16*)p;            p += NE * 2;
    __bf16* W1b  = (__bf16*)p;            p += NW * 2;
    __bf16* Wdb  = (__bf16*)p;            p += NW * 2;
    __bf16* hb   = (__bf16*)p;            p += NE * 2;
    __bf16* hlnb = (__bf16*)p;            p += NE * 2;
    __bf16* embb = (__bf16*)p;            p += NE * 2;
    float*  pm   = (float*)p;             p += (size_t)ROWS * NSPLIT * 4;
    float*  ps   = (float*)p;             p += (size_t)ROWS * NSPLIT * 4;
    float*  diag = (float*)p;             p += (size_t)ROWS * 4;

    hipFuncSetAttribute((const void*)k_lse8p, hipFuncAttributeMaxDynamicSharedMemorySize,
                        131072);

    // convert fp32 -> bf16 (x+labels in one launch, W1+Wd in another)
    k_f2bf2<<<(2 * NE / 4) / 256, 256, 0, stream>>>(x, labels, xb, labb, (int)NE);
    k_f2bf2<<<(2 * NW / 4) / 256, 256, 0, stream>>>(W1, Wd, W1b, Wdb, (int)NW);

    // MFM block (LDS-staged GEMMs)
    dim3 g1(ROWS / 128, DPOS / 128);
    k_gemm_ld<0><<<g1, 256, 0, stream>>>(xb, W1b, b1, hb);
    k_ln<<<ROWS, 256, 0, stream>>>(hb, ln_g, ln_b, hlnb);
    k_gemm_ld<1><<<g1, 256, 0, stream>>>(hlnb, Wdb, b_dec, embb);

    // contrastive loss
    dim3 g2(ROWS / BM, NSPLIT);
    k_lse8p<<<g2, 512, 131072, stream>>>(embb, labb, vm, pm, ps);
    k_diag<<<ROWS / 4, 256, 0, stream>>>(embb, labb, diag);
    k_loss<<<1, 256, 0, stream>>>(pm, ps, diag, lidx, out);
}

// Round 10
// 247.913 us; speedup vs baseline: 1.3256x; 1.3256x over previous
//
#include <hip/hip_runtime.h>
#include <hip/hip_bf16.h>
#include <math.h>

#define DPOS 768
#define ROWS 8192           // 32*256
#define NEG_INF_V (-10000.0f)
#define NSPLIT 16

// ---- small-footprint 2-phase geometry for k_lse_sb2 ----
#define BM 64
#define BN 128
#define BK 64
#define CPS (ROWS / NSPLIT)   // cols per split = 512
#define NCT (CPS / BN)        // col-tiles per block = 4
#define NKC (DPOS / BK)       // K-chunks per col-tile = 12

typedef __attribute__((ext_vector_type(8))) __bf16 bf16x8;
typedef __attribute__((ext_vector_type(4))) __bf16 bf16x4;
typedef __attribute__((ext_vector_type(4))) float f32x4;

typedef const __attribute__((address_space(1))) unsigned int* gptr_t;
typedef __attribute__((address_space(3))) unsigned int* lptr_t;

// ---------------- fp32 -> bf16 conversion (two arrays per launch) ----------------
__global__ __launch_bounds__(256) void k_f2bf2(const float* __restrict__ a,
                                               const float* __restrict__ b,
                                               __bf16* __restrict__ da,
                                               __bf16* __restrict__ db, int n) {
    int i = (blockIdx.x * blockDim.x + threadIdx.x) * 4;
    const float* s = (i < n) ? a : b;
    __bf16* d = (i < n) ? da : db;
    int j = (i < n) ? i : i - n;
    float4 v = *(const float4*)(s + j);
    bf16x4 o = {(__bf16)v.x, (__bf16)v.y, (__bf16)v.z, (__bf16)v.w};
    *(bf16x4*)(d + j) = o;
}

// ---------------- LDS-staged GEMM C = A * B^T (+bias, epilogue), bf16 out ----------
template <int MODE>
__global__ __launch_bounds__(256, 3) void k_gemm_ld(const __bf16* __restrict__ A,
                                                    const __bf16* __restrict__ B,
                                                    const float* __restrict__ bias,
                                                    __bf16* __restrict__ outB) {
    __shared__ __align__(16) char sAB[32768];   // A[128][64]@0, B[128][64]@16384

    const int tid = threadIdx.x;
    const int lane = tid & 63;
    const int wave = tid >> 6;
    const int wr = wave >> 1, wc = wave & 1;
    const int lr = lane & 15;
    const int lk = (lane >> 4) * 8;
    const int rr = (lane >> 4) * 4;
    const int row0 = blockIdx.x * 128;
    const int col0 = blockIdx.y * 128;

    int o[4];
    const char* As[4];
    const char* Bs[4];
#pragma unroll
    for (int c = 0; c < 4; ++c) {
        int off = tid * 16 + c * 4096;
        int row = off >> 7;
        int scol = (off & 127) ^ ((row & 7) << 4);
        o[c] = off;
        As[c] = (const char*)A + ((size_t)(row0 + row)) * (DPOS * 2) + scol;
        Bs[c] = (const char*)B + ((size_t)(col0 + row)) * (DPOS * 2) + scol;
    }

    const int sws = (lr & 7) << 4;
    const int colK0 = (lk * 2) ^ sws;
    const int colK1 = (lk * 2 + 64) ^ sws;
    const int aB0 = (wr * 64 + lr) * 128 + colK0, aB1 = (wr * 64 + lr) * 128 + colK1;
    const int bB0 = 16384 + (wc * 64 + lr) * 128 + colK0;
    const int bB1 = 16384 + (wc * 64 + lr) * 128 + colK1;

    f32x4 acc[4][4];
#pragma unroll
    for (int i = 0; i < 4; ++i)
#pragma unroll
        for (int j = 0; j < 4; ++j) acc[i][j] = (f32x4){0.f, 0.f, 0.f, 0.f};

#pragma unroll 1
    for (int kc = 0; kc < DPOS / 64; ++kc) {
        const int kb = kc * 128;
#pragma unroll
        for (int c = 0; c < 4; ++c) {
            __builtin_amdgcn_global_load_lds((gptr_t)(As[c] + kb),
                                             (lptr_t)(sAB + o[c]), 16, 0, 0);
            __builtin_amdgcn_global_load_lds((gptr_t)(Bs[c] + kb),
                                             (lptr_t)(sAB + 16384 + o[c]), 16, 0, 0);
        }
        __syncthreads();
#pragma unroll
        for (int kk = 0; kk < 2; ++kk) {
            const int aBase = kk ? aB1 : aB0;
            const int bBase = kk ? bB1 : bB0;
            bf16x8 af[4], bf_[4];
#pragma unroll
            for (int mi = 0; mi < 4; ++mi)
                af[mi] = *(const bf16x8*)(sAB + aBase + mi * 2048);
#pragma unroll
            for (int ni = 0; ni < 4; ++ni)
                bf_[ni] = *(const bf16x8*)(sAB + bBase + ni * 2048);
#pragma unroll
            for (int i = 0; i < 4; ++i)
#pragma unroll
                for (int j = 0; j < 4; ++j)
                    acc[i][j] = __builtin_amdgcn_mfma_f32_16x16x32_bf16(
                        af[i], bf_[j], acc[i][j], 0, 0, 0);
        }
        __syncthreads();
    }

#pragma unroll
    for (int j = 0; j < 4; ++j) {
        int col = col0 + wc * 64 + j * 16 + lr;
        float bv = bias[col];
#pragma unroll
        for (int i = 0; i < 4; ++i)
#pragma unroll
            for (int v = 0; v < 4; ++v) {
                int row = row0 + wr * 64 + i * 16 + rr + v;
                float val = acc[i][j][v] + bv;
                if (MODE == 0)
                    val = 0.5f * val * (1.0f + erff(val * 0.70710678118654752f));
                outB[(size_t)row * DPOS + col] = (__bf16)val;
            }
    }
}

// ---------------- LayerNorm over last dim (768), one block per row, bf16 in/out ----------------
__global__ __launch_bounds__(256) void k_ln(const __bf16* __restrict__ h,
                                            const float* __restrict__ g,
                                            const float* __restrict__ bta,
                                            __bf16* __restrict__ out) {
    int row = blockIdx.x;
    const __bf16* hr = h + (size_t)row * DPOS;
    float v[3], s = 0.f, sq = 0.f;
#pragma unroll
    for (int t = 0; t < 3; ++t) {
        v[t] = (float)hr[threadIdx.x + t * 256];
        s += v[t];
        sq += v[t] * v[t];
    }
#pragma unroll
    for (int m = 32; m >= 1; m >>= 1) {
        s += __shfl_xor(s, m);
        sq += __shfl_xor(sq, m);
    }
    __shared__ float ss[4], sqq[4];
    int wave = threadIdx.x >> 6, lane = threadIdx.x & 63;
    if (lane == 0) { ss[wave] = s; sqq[wave] = sq; }
    __syncthreads();
    s = ss[0] + ss[1] + ss[2] + ss[3];
    sq = sqq[0] + sqq[1] + sqq[2] + sqq[3];
    float mu = s * (1.0f / DPOS);
    float var = sq * (1.0f / DPOS) - mu * mu;
    float r = rsqrtf(var + 1e-12f);
#pragma unroll
    for (int t = 0; t < 3; ++t) {
        int c = threadIdx.x + t * 256;
        out[(size_t)row * DPOS + c] = (__bf16)((v[t] - mu) * r * g[c] + bta[c]);
    }
}

// ---------------- fused logits + logsumexp: small-footprint 2-phase ----------------
// BM=64 x BN=128 block tile, 4 waves (2wr x 2wc), wave tile 32x64. LDS 27.6 KB
// (A[64][64]@0 8KB, B[128][64]@8192 16KB, svm 2KB, merge 1KB) -> target 4+ blocks/CU
// (TLP latency hiding, m97/m114 mechanism). Grid (ROWS/64, NSPLIT) = 2048 blocks.
__global__ __launch_bounds__(256, 4) void k_lse_sb2(const __bf16* __restrict__ E,
                                                    const __bf16* __restrict__ L,
                                                    const float* __restrict__ vm,
                                                    float* __restrict__ pm,
                                                    float* __restrict__ ps) {
    __shared__ __align__(16) char sAB[24576];   // A@0 (8KB), B@8192 (16KB)
    __shared__ float svm[CPS];                  // 2 KB
    __shared__ float smm[2][64], sms[2][64];    // 1 KB

    const int tid = threadIdx.x;
    const int lane = tid & 63;
    const int wave = tid >> 6;
    const int wr = wave >> 1, wc = wave & 1;
    const int lr = lane & 15;
    const int lk = (lane >> 4) * 8;
    const int rr = (lane >> 4) * 4;
    const int split = blockIdx.y;
    const int row0 = blockIdx.x * BM;

    // column-mask values for this split -> LDS (read only in epilogue, behind barriers)
    svm[tid] = vm[split * CPS + tid];
    svm[tid + 256] = vm[split * CPS + tid + 256];

    // row-mask bits: 8 rows per lane (mi 0..1, v 0..3)
    unsigned mrow = 0;
#pragma unroll
    for (int mi = 0; mi < 2; ++mi) {
        float4 mv = *(const float4*)(vm + row0 + wr * 32 + mi * 16 + rr);
        if (mv.x != 0.f) mrow |= 1u << (mi * 4 + 0);
        if (mv.y != 0.f) mrow |= 1u << (mi * 4 + 1);
        if (mv.z != 0.f) mrow |= 1u << (mi * 4 + 2);
        if (mv.w != 0.f) mrow |= 1u << (mi * 4 + 3);
    }

    // staging geometry: A 2 x 16B per thread (8KB), B 4 x 16B (16KB)
    int oA[2], oB[4];
    const char* EsA[2];
    const char* LsB[4];
#pragma unroll
    for (int c = 0; c < 2; ++c) {
        int off = tid * 16 + c * 4096;
        int row = off >> 7;                       // 0..63
        int scol = (off & 127) ^ ((row & 7) << 4);
        oA[c] = off;
        EsA[c] = (const char*)E + ((size_t)(row0 + row)) * (DPOS * 2) + scol;
    }
#pragma unroll
    for (int c = 0; c < 4; ++c) {
        int off = tid * 16 + c * 4096;
        int row = off >> 7;                       // 0..127
        int scol = (off & 127) ^ ((row & 7) << 4);
        oB[c] = 8192 + off;
        LsB[c] = (const char*)L + ((size_t)(split * CPS + row)) * (DPOS * 2) + scol;
    }

    // ds_read lane-constant bases
    const int sws = (lr & 7) << 4;
    const int colK0 = (lk * 2) ^ sws;
    const int colK1 = (lk * 2 + 64) ^ sws;
    const int aB0 = (wr * 32 + lr) * 128 + colK0, aB1 = (wr * 32 + lr) * 128 + colK1;
    const int bB0 = 8192 + (wc * 64 + lr) * 128 + colK0;
    const int bB1 = 8192 + (wc * 64 + lr) * 128 + colK1;

    float Mrun = -1e30f, Srun = 0.f;

#pragma unroll 1
    for (int ct = 0; ct < NCT; ++ct) {
        f32x4 acc[2][4];
#pragma unroll
        for (int i = 0; i < 2; ++i)
#pragma unroll
            for (int j = 0; j < 4; ++j) acc[i][j] = (f32x4){0.f, 0.f, 0.f, 0.f};

        const long ctb = (long)ct * BN * (DPOS * 2);

#pragma unroll 1
        for (int kc = 0; kc < NKC; ++kc) {
            const int kb = kc * (BK * 2);
#pragma unroll
            for (int c = 0; c < 2; ++c)
                __builtin_amdgcn_global_load_lds((gptr_t)(EsA[c] + kb),
                                                 (lptr_t)(sAB + oA[c]), 16, 0, 0);
#pragma unroll
            for (int c = 0; c < 4; ++c)
                __builtin_amdgcn_global_load_lds((gptr_t)(LsB[c] + ctb + kb),
                                                 (lptr_t)(sAB + oB[c]), 16, 0, 0);
            __syncthreads();
#pragma unroll
            for (int kk = 0; kk < 2; ++kk) {
                const int aBase = kk ? aB1 : aB0;
                const int bBase = kk ? bB1 : bB0;
                bf16x8 af[2], bf_[4];
#pragma unroll
                for (int mi = 0; mi < 2; ++mi)
                    af[mi] = *(const bf16x8*)(sAB + aBase + mi * 2048);
#pragma unroll
                for (int ni = 0; ni < 4; ++ni)
                    bf_[ni] = *(const bf16x8*)(sAB + bBase + ni * 2048);
#pragma unroll
                for (int i = 0; i < 2; ++i)
#pragma unroll
                    for (int j = 0; j < 4; ++j)
                        acc[i][j] = __builtin_amdgcn_mfma_f32_16x16x32_bf16(
                            af[i], bf_[j], acc[i][j], 0, 0, 0);
            }
            __syncthreads();
        }

        // ---- epilogue: online softmax over this 64x128 logits tile ----
        float cmv[4];
#pragma unroll
        for (int ni = 0; ni < 4; ++ni) cmv[ni] = svm[ct * BN + wc * 64 + ni * 16 + lr];
#pragma unroll
        for (int mi = 0; mi < 2; ++mi)
#pragma unroll
            for (int v = 0; v < 4; ++v) {
                bool rv = (mrow >> (mi * 4 + v)) & 1u;
                float x0 = acc[mi][0][v] + ((rv && cmv[0] == 0.f) ? NEG_INF_V : 0.f);
                float x1 = acc[mi][1][v] + ((rv && cmv[1] == 0.f) ? NEG_INF_V : 0.f);
                float x2 = acc[mi][2][v] + ((rv && cmv[2] == 0.f) ? NEG_INF_V : 0.f);
                float x3 = acc[mi][3][v] + ((rv && cmv[3] == 0.f) ? NEG_INF_V : 0.f);
                float m4 = fmaxf(fmaxf(x0, x1), fmaxf(x2, x3));
                float s4 = __expf(x0 - m4) + __expf(x1 - m4) +
                           __expf(x2 - m4) + __expf(x3 - m4);
#pragma unroll
                for (int d = 1; d < 16; d <<= 1) {
                    float mo = __shfl_xor(m4, d);
                    float so = __shfl_xor(s4, d);
                    float nm = fmaxf(m4, mo);
                    s4 = s4 * __expf(m4 - nm) + so * __expf(mo - nm);
                    m4 = nm;
                }
                if (lr == 0) {
                    smm[wc][wr * 32 + mi * 16 + rr + v] = m4;
                    sms[wc][wr * 32 + mi * 16 + rr + v] = s4;
                }
            }
        __syncthreads();
        if (tid < 64) {
            float m0 = smm[0][tid], s0 = sms[0][tid];
            float m1 = smm[1][tid], s1 = sms[1][tid];
            float nm = fmaxf(m0, m1);
            float s = s0 * __expf(m0 - nm) + s1 * __expf(m1 - nm);
            float nm2 = fmaxf(Mrun, nm);
            Srun = Srun * __expf(Mrun - nm2) + s * __expf(nm - nm2);
            Mrun = nm2;
        }
        __syncthreads();   // smm consumed before next ct's epilogue rewrites it
    }

    if (tid < 64) {
        size_t idx = (size_t)(row0 + tid) * NSPLIT + split;
        pm[idx] = Mrun;
        ps[idx] = Srun;
    }
}

// ---------------- diagonal: diag[i] = dot(emb_i, labels_i) ----------------
__global__ __launch_bounds__(256) void k_diag(const __bf16* __restrict__ E,
                                              const __bf16* __restrict__ L,
                                              float* __restrict__ diag) {
    int wave = threadIdx.x >> 6, lane = threadIdx.x & 63;
    int row = blockIdx.x * 4 + wave;
    const __bf16* e = E + (size_t)row * DPOS;
    const __bf16* l = L + (size_t)row * DPOS;
    float s = 0.f;
    for (int k = lane * 8; k < DPOS; k += 64 * 8) {
        bf16x8 a = *(const bf16x8*)(e + k);
        bf16x8 b = *(const bf16x8*)(l + k);
#pragma unroll
        for (int j = 0; j < 8; ++j) s += (float)a[j] * (float)b[j];
    }
#pragma unroll
    for (int m = 32; m >= 1; m >>= 1) s += __shfl_xor(s, m);
    if (lane == 0) diag[row] = s;
}

// ---------------- combine partials + masked mean ----------------
__global__ __launch_bounds__(256) void k_loss(const float* __restrict__ pm,
                                              const float* __restrict__ ps,
                                              const float* __restrict__ diag,
                                              const int* __restrict__ idx,
                                              float* __restrict__ out) {
    float accn = 0.f, accd = 0.f;
    for (int i = threadIdx.x; i < ROWS; i += 256) {
        float m = pm[i * NSPLIT + 0], s = ps[i * NSPLIT + 0];
#pragma unroll
        for (int c = 1; c < NSPLIT; ++c) {
            float mo = pm[i * NSPLIT + c], so = ps[i * NSPLIT + c];
            float nm = fmaxf(m, mo);
            s = s * __expf(m - nm) + so * __expf(mo - nm);
            m = nm;
        }
        float lse = m + logf(s);
        bool valid = (idx[i] != -100);
        if (valid) {
            accn += diag[i] - lse;
            accd += 1.f;
        }
    }
#pragma unroll
    for (int m = 32; m >= 1; m >>= 1) {
        accn += __shfl_xor(accn, m);
        accd += __shfl_xor(accd, m);
    }
    __shared__ float an[4], ad[4];
    int wave = threadIdx.x >> 6, lane = threadIdx.x & 63;
    if (lane == 0) { an[wave] = accn; ad[wave] = accd; }
    __syncthreads();
    if (threadIdx.x == 0) {
        float n = an[0] + an[1] + an[2] + an[3];
        float d = ad[0] + ad[1] + ad[2] + ad[3];
        out[0] = -n / d;
    }
}

extern "C" void kernel_launch(void* const* d_in, const int* in_sizes, int n_in,
                              void* d_out, int out_size, void* d_ws, size_t ws_size,
                              hipStream_t stream) {
    const float* x      = (const float*)d_in[0];   // [8192][768]
    const float* labels = (const float*)d_in[1];   // [8192][768]
    const int*   lidx   = (const int*)d_in[2];     // [8192]
    const float* vm     = (const float*)d_in[3];   // [8192]
    const float* W1     = (const float*)d_in[4];   // [768][768]
    const float* b1     = (const float*)d_in[5];
    const float* ln_g   = (const float*)d_in[6];
    const float* ln_b   = (const float*)d_in[7];
    const float* Wd     = (const float*)d_in[8];
    const float* b_dec  = (const float*)d_in[9];
    float* out = (float*)d_out;

    const size_t NE = (size_t)ROWS * DPOS;       // 6291456
    const size_t NW = (size_t)DPOS * DPOS;       // 589824
    char* p = (char*)d_ws;
    __bf16* xb   = (__bf16*)p;            p += NE * 2;
    __bf16* labb = (__bf16*)p;            p += NE * 2;
    __bf16* W1b  = (__bf16*)p;            p += NW * 2;
    __bf16* Wdb  = (__bf16*)p;            p += NW * 2;
    __bf16* hb   = (__bf16*)p;            p += NE * 2;
    __bf16* hlnb = (__bf16*)p;            p += NE * 2;
    __bf16* embb = (__bf16*)p;            p += NE * 2;
    float*  pm   = (float*)p;             p += (size_t)ROWS * NSPLIT * 4;
    float*  ps   = (float*)p;             p += (size_t)ROWS * NSPLIT * 4;
    float*  diag = (float*)p;             p += (size_t)ROWS * 4;

    // convert fp32 -> bf16 (x+labels in one launch, W1+Wd in another)
    k_f2bf2<<<(2 * NE / 4) / 256, 256, 0, stream>>>(x, labels, xb, labb, (int)NE);
    k_f2bf2<<<(2 * NW / 4) / 256, 256, 0, stream>>>(W1, Wd, W1b, Wdb, (int)NW);

    // MFM block (LDS-staged GEMMs)
    dim3 g1(ROWS / 128, DPOS / 128);
    k_gemm_ld<0><<<g1, 256, 0, stream>>>(xb, W1b, b1, hb);
    k_ln<<<ROWS, 256, 0, stream>>>(hb, ln_g, ln_b, hlnb);
    k_gemm_ld<1><<<g1, 256, 0, stream>>>(hlnb, Wdb, b_dec, embb);

    // contrastive loss
    dim3 g2(ROWS / BM, NSPLIT);
    k_lse_sb2<<<g2, 256, 0, stream>>>(embb, labb, vm, pm, ps);
    k_diag<<<ROWS / 4, 256, 0, stream>>>(embb, labb, diag);
    k_loss<<<1, 256, 0, stream>>>(pm, ps, diag, lidx, out);
}

// Round 11
// 218.440 us; speedup vs baseline: 1.5045x; 1.1349x over previous
//
#include <hip/hip_runtime.h>
#include <hip/hip_bf16.h>
#include <math.h>

#define DPOS 768
#define ROWS 8192           // 32*256
#define NEG_INF_V (-10000.0f)
#define NSPLIT 16

// ---- k_lse_sb3 geometry: 128x128 tile, 32 KB LDS exactly ----
#define BM 128
#define BN 128
#define BK 64
#define CPS (ROWS / NSPLIT)   // cols per split = 512
#define NCT (CPS / BN)        // col-tiles per block = 4
#define NKC (DPOS / BK)       // K-chunks per col-tile = 12

typedef __attribute__((ext_vector_type(8))) __bf16 bf16x8;
typedef __attribute__((ext_vector_type(4))) __bf16 bf16x4;
typedef __attribute__((ext_vector_type(4))) float f32x4;

typedef const __attribute__((address_space(1))) unsigned int* gptr_t;
typedef __attribute__((address_space(3))) unsigned int* lptr_t;

// ---------------- fp32 -> bf16 conversion (two arrays per launch) ----------------
__global__ __launch_bounds__(256) void k_f2bf2(const float* __restrict__ a,
                                               const float* __restrict__ b,
                                               __bf16* __restrict__ da,
                                               __bf16* __restrict__ db, int n) {
    int i = (blockIdx.x * blockDim.x + threadIdx.x) * 4;
    const float* s = (i < n) ? a : b;
    __bf16* d = (i < n) ? da : db;
    int j = (i < n) ? i : i - n;
    float4 v = *(const float4*)(s + j);
    bf16x4 o = {(__bf16)v.x, (__bf16)v.y, (__bf16)v.z, (__bf16)v.w};
    *(bf16x4*)(d + j) = o;
}

// ---------------- LDS-staged GEMM C = A * B^T (+bias), bf16 out, 64x128 tile ------
// 4 waves (2x2), wave tile 32x64. LDS 24 KB (-> 32 KB granule) => 3+ blocks/CU.
// Grid (ROWS/64, DPOS/128) = (128, 6) = 768 blocks.
template <int MODE>
__global__ __launch_bounds__(256, 4) void k_gemm_ld(const __bf16* __restrict__ A,
                                                    const __bf16* __restrict__ B,
                                                    const float* __restrict__ bias,
                                                    __bf16* __restrict__ outB) {
    __shared__ __align__(16) char sAB[24576];   // A[64][64]@0 (8KB), B[128][64]@8192 (16KB)

    const int tid = threadIdx.x;
    const int lane = tid & 63;
    const int wave = tid >> 6;
    const int wr = wave >> 1, wc = wave & 1;
    const int lr = lane & 15;
    const int lk = (lane >> 4) * 8;
    const int rr = (lane >> 4) * 4;
    const int row0 = blockIdx.x * 64;
    const int col0 = blockIdx.y * 128;

    int oA[2], oB[4];
    const char* As[2];
    const char* Bs[4];
#pragma unroll
    for (int c = 0; c < 2; ++c) {
        int off = tid * 16 + c * 4096;
        int row = off >> 7;                       // 0..63
        int scol = (off & 127) ^ ((row & 7) << 4);
        oA[c] = off;
        As[c] = (const char*)A + ((size_t)(row0 + row)) * (DPOS * 2) + scol;
    }
#pragma unroll
    for (int c = 0; c < 4; ++c) {
        int off = tid * 16 + c * 4096;
        int row = off >> 7;                       // 0..127
        int scol = (off & 127) ^ ((row & 7) << 4);
        oB[c] = 8192 + off;
        Bs[c] = (const char*)B + ((size_t)(col0 + row)) * (DPOS * 2) + scol;
    }

    const int sws = (lr & 7) << 4;
    const int colK0 = (lk * 2) ^ sws;
    const int colK1 = (lk * 2 + 64) ^ sws;
    const int aB0 = (wr * 32 + lr) * 128 + colK0, aB1 = (wr * 32 + lr) * 128 + colK1;
    const int bB0 = 8192 + (wc * 64 + lr) * 128 + colK0;
    const int bB1 = 8192 + (wc * 64 + lr) * 128 + colK1;

    f32x4 acc[2][4];
#pragma unroll
    for (int i = 0; i < 2; ++i)
#pragma unroll
        for (int j = 0; j < 4; ++j) acc[i][j] = (f32x4){0.f, 0.f, 0.f, 0.f};

#pragma unroll 1
    for (int kc = 0; kc < NKC; ++kc) {
        const int kb = kc * 128;
#pragma unroll
        for (int c = 0; c < 2; ++c)
            __builtin_amdgcn_global_load_lds((gptr_t)(As[c] + kb),
                                             (lptr_t)(sAB + oA[c]), 16, 0, 0);
#pragma unroll
        for (int c = 0; c < 4; ++c)
            __builtin_amdgcn_global_load_lds((gptr_t)(Bs[c] + kb),
                                             (lptr_t)(sAB + oB[c]), 16, 0, 0);
        __syncthreads();
#pragma unroll
        for (int kk = 0; kk < 2; ++kk) {
            const int aBase = kk ? aB1 : aB0;
            const int bBase = kk ? bB1 : bB0;
            bf16x8 af[2], bf_[4];
#pragma unroll
            for (int mi = 0; mi < 2; ++mi)
                af[mi] = *(const bf16x8*)(sAB + aBase + mi * 2048);
#pragma unroll
            for (int ni = 0; ni < 4; ++ni)
                bf_[ni] = *(const bf16x8*)(sAB + bBase + ni * 2048);
#pragma unroll
            for (int i = 0; i < 2; ++i)
#pragma unroll
                for (int j = 0; j < 4; ++j)
                    acc[i][j] = __builtin_amdgcn_mfma_f32_16x16x32_bf16(
                        af[i], bf_[j], acc[i][j], 0, 0, 0);
        }
        __syncthreads();
    }

#pragma unroll
    for (int j = 0; j < 4; ++j) {
        int col = col0 + wc * 64 + j * 16 + lr;
        float bv = bias[col];
#pragma unroll
        for (int i = 0; i < 2; ++i)
#pragma unroll
            for (int v = 0; v < 4; ++v) {
                int row = row0 + wr * 32 + i * 16 + rr + v;
                float val = acc[i][j][v] + bv;
                if (MODE == 0)
                    val = 0.5f * val * (1.0f + erff(val * 0.70710678118654752f));
                outB[(size_t)row * DPOS + col] = (__bf16)val;
            }
    }
}

// ---------------- LayerNorm over last dim (768), one block per row, bf16 in/out ----------------
__global__ __launch_bounds__(256) void k_ln(const __bf16* __restrict__ h,
                                            const float* __restrict__ g,
                                            const float* __restrict__ bta,
                                            __bf16* __restrict__ out) {
    int row = blockIdx.x;
    const __bf16* hr = h + (size_t)row * DPOS;
    float v[3], s = 0.f, sq = 0.f;
#pragma unroll
    for (int t = 0; t < 3; ++t) {
        v[t] = (float)hr[threadIdx.x + t * 256];
        s += v[t];
        sq += v[t] * v[t];
    }
#pragma unroll
    for (int m = 32; m >= 1; m >>= 1) {
        s += __shfl_xor(s, m);
        sq += __shfl_xor(sq, m);
    }
    __shared__ float ss[4], sqq[4];
    int wave = threadIdx.x >> 6, lane = threadIdx.x & 63;
    if (lane == 0) { ss[wave] = s; sqq[wave] = sq; }
    __syncthreads();
    s = ss[0] + ss[1] + ss[2] + ss[3];
    sq = sqq[0] + sqq[1] + sqq[2] + sqq[3];
    float mu = s * (1.0f / DPOS);
    float var = sq * (1.0f / DPOS) - mu * mu;
    float r = rsqrtf(var + 1e-12f);
#pragma unroll
    for (int t = 0; t < 3; ++t) {
        int c = threadIdx.x + t * 256;
        out[(size_t)row * DPOS + c] = (__bf16)((v[t] - mu) * r * g[c] + bta[c]);
    }
}

// ---------------- fused logits + logsumexp: 128x128 tile in EXACTLY 32 KB LDS ------
// 4 waves (2x2), wave tile 64x64. No svm (vm read from global in epilogue; the
// __syncthreads vmcnt-drain makes it safe); merge buffers reuse sAB (epilogue runs
// behind the chunk-loop's final barrier). Two-pass epilogue: max-reduce then
// sum-reduce (4 exps/slot). Target 4-5 blocks/CU. Grid (ROWS/128, NSPLIT).
__global__ __launch_bounds__(256, 4) void k_lse_sb3(const __bf16* __restrict__ E,
                                                    const __bf16* __restrict__ L,
                                                    const float* __restrict__ vm,
                                                    float* __restrict__ pm,
                                                    float* __restrict__ ps) {
    __shared__ __align__(16) char sAB[32768];   // A[128][64]@0, B[128][64]@16384

    const int tid = threadIdx.x;
    const int lane = tid & 63;
    const int wave = tid >> 6;
    const int wr = wave >> 1, wc = wave & 1;
    const int lr = lane & 15;
    const int lk = (lane >> 4) * 8;
    const int rr = (lane >> 4) * 4;
    const int split = blockIdx.y;
    const int row0 = blockIdx.x * BM;

    // merge scratch aliased onto sAB (used only between barriers in the epilogue)
    float* smm = (float*)sAB;            // [2][128]
    float* sms = (float*)(sAB + 1024);   // [2][128]

    // row-mask bits: 16 rows per lane (mi 0..3, v 0..3)
    unsigned mrow = 0;
#pragma unroll
    for (int mi = 0; mi < 4; ++mi) {
        float4 mv = *(const float4*)(vm + row0 + wr * 64 + mi * 16 + rr);
        if (mv.x != 0.f) mrow |= 1u << (mi * 4 + 0);
        if (mv.y != 0.f) mrow |= 1u << (mi * 4 + 1);
        if (mv.z != 0.f) mrow |= 1u << (mi * 4 + 2);
        if (mv.w != 0.f) mrow |= 1u << (mi * 4 + 3);
    }

    // staging geometry: 4 x 16B per thread per operand (16 KB each)
    int o[4];
    const char* EsA[4];
    const char* LsB[4];
#pragma unroll
    for (int c = 0; c < 4; ++c) {
        int off = tid * 16 + c * 4096;
        int row = off >> 7;                       // 0..127
        int scol = (off & 127) ^ ((row & 7) << 4);
        o[c] = off;
        EsA[c] = (const char*)E + ((size_t)(row0 + row)) * (DPOS * 2) + scol;
        LsB[c] = (const char*)L + ((size_t)(split * CPS + row)) * (DPOS * 2) + scol;
    }

    const int sws = (lr & 7) << 4;
    const int colK0 = (lk * 2) ^ sws;
    const int colK1 = (lk * 2 + 64) ^ sws;
    const int aB0 = (wr * 64 + lr) * 128 + colK0, aB1 = (wr * 64 + lr) * 128 + colK1;
    const int bB0 = 16384 + (wc * 64 + lr) * 128 + colK0;
    const int bB1 = 16384 + (wc * 64 + lr) * 128 + colK1;

    float Mrun = -1e30f, Srun = 0.f;

#pragma unroll 1
    for (int ct = 0; ct < NCT; ++ct) {
        f32x4 acc[4][4];
#pragma unroll
        for (int i = 0; i < 4; ++i)
#pragma unroll
            for (int j = 0; j < 4; ++j) acc[i][j] = (f32x4){0.f, 0.f, 0.f, 0.f};

        const long ctb = (long)ct * BN * (DPOS * 2);

#pragma unroll 1
        for (int kc = 0; kc < NKC; ++kc) {
            const int kb = kc * (BK * 2);
#pragma unroll
            for (int c = 0; c < 4; ++c) {
                __builtin_amdgcn_global_load_lds((gptr_t)(EsA[c] + kb),
                                                 (lptr_t)(sAB + o[c]), 16, 0, 0);
                __builtin_amdgcn_global_load_lds((gptr_t)(LsB[c] + ctb + kb),
                                                 (lptr_t)(sAB + 16384 + o[c]), 16, 0, 0);
            }
            __syncthreads();
#pragma unroll
            for (int kk = 0; kk < 2; ++kk) {
                const int aBase = kk ? aB1 : aB0;
                const int bBase = kk ? bB1 : bB0;
                bf16x8 af[4], bf_[4];
#pragma unroll
                for (int mi = 0; mi < 4; ++mi)
                    af[mi] = *(const bf16x8*)(sAB + aBase + mi * 2048);
#pragma unroll
                for (int ni = 0; ni < 4; ++ni)
                    bf_[ni] = *(const bf16x8*)(sAB + bBase + ni * 2048);
#pragma unroll
                for (int i = 0; i < 4; ++i)
#pragma unroll
                    for (int j = 0; j < 4; ++j)
                        acc[i][j] = __builtin_amdgcn_mfma_f32_16x16x32_bf16(
                            af[i], bf_[j], acc[i][j], 0, 0, 0);
            }
            __syncthreads();
        }

        // ---- two-pass epilogue over this 128x128 logits tile ----
        // column-mask additive terms (global reads; barrier below drains them)
        float addv[4];
#pragma unroll
        for (int ni = 0; ni < 4; ++ni)
            addv[ni] = (vm[split * CPS + ct * BN + wc * 64 + ni * 16 + lr] == 0.f)
                           ? NEG_INF_V : 0.f;

        float m16[16], s16[16];
#pragma unroll
        for (int mi = 0; mi < 4; ++mi)
#pragma unroll
            for (int v = 0; v < 4; ++v) {
                const int ri = mi * 4 + v;
                bool rv = (mrow >> ri) & 1u;
                float x0 = acc[mi][0][v] + (rv ? addv[0] : 0.f);
                float x1 = acc[mi][1][v] + (rv ? addv[1] : 0.f);
                float x2 = acc[mi][2][v] + (rv ? addv[2] : 0.f);
                float x3 = acc[mi][3][v] + (rv ? addv[3] : 0.f);
                float m4 = fmaxf(fmaxf(x0, x1), fmaxf(x2, x3));
#pragma unroll
                for (int d = 1; d < 16; d <<= 1) m4 = fmaxf(m4, __shfl_xor(m4, d));
                float s4 = __expf(x0 - m4) + __expf(x1 - m4) +
                           __expf(x2 - m4) + __expf(x3 - m4);
#pragma unroll
                for (int d = 1; d < 16; d <<= 1) s4 += __shfl_xor(s4, d);
                m16[ri] = m4;
                s16[ri] = s4;
            }
        // write per-row (m,s) into the aliased merge buffers
        if (lr == 0) {
#pragma unroll
            for (int mi = 0; mi < 4; ++mi)
#pragma unroll
                for (int v = 0; v < 4; ++v) {
                    int rl = wr * 64 + mi * 16 + rr + v;
                    smm[wc * 128 + rl] = m16[mi * 4 + v];
                    sms[wc * 128 + rl] = s16[mi * 4 + v];
                }
        }
        __syncthreads();
        if (tid < 128) {
            float m0 = smm[tid], s0 = sms[tid];
            float m1 = smm[128 + tid], s1 = sms[128 + tid];
            float nm = fmaxf(m0, m1);
            float s = s0 * __expf(m0 - nm) + s1 * __expf(m1 - nm);
            float nm2 = fmaxf(Mrun, nm);
            Srun = Srun * __expf(Mrun - nm2) + s * __expf(nm - nm2);
            Mrun = nm2;
        }
        __syncthreads();   // merge consumed before next ct's staging overwrites sAB
    }

    if (tid < 128) {
        size_t idx = (size_t)(row0 + tid) * NSPLIT + split;
        pm[idx] = Mrun;
        ps[idx] = Srun;
    }
}

// ---------------- diagonal: diag[i] = dot(emb_i, labels_i) ----------------
__global__ __launch_bounds__(256) void k_diag(const __bf16* __restrict__ E,
                                              const __bf16* __restrict__ L,
                                              float* __restrict__ diag) {
    int wave = threadIdx.x >> 6, lane = threadIdx.x & 63;
    int row = blockIdx.x * 4 + wave;
    const __bf16* e = E + (size_t)row * DPOS;
    const __bf16* l = L + (size_t)row * DPOS;
    float s = 0.f;
    for (int k = lane * 8; k < DPOS; k += 64 * 8) {
        bf16x8 a = *(const bf16x8*)(e + k);
        bf16x8 b = *(const bf16x8*)(l + k);
#pragma unroll
        for (int j = 0; j < 8; ++j) s += (float)a[j] * (float)b[j];
    }
#pragma unroll
    for (int m = 32; m >= 1; m >>= 1) s += __shfl_xor(s, m);
    if (lane == 0) diag[row] = s;
}

// ---------------- combine partials + masked mean ----------------
__global__ __launch_bounds__(256) void k_loss(const float* __restrict__ pm,
                                              const float* __restrict__ ps,
                                              const float* __restrict__ diag,
                                              const int* __restrict__ idx,
                                              float* __restrict__ out) {
    float accn = 0.f, accd = 0.f;
    for (int i = threadIdx.x; i < ROWS; i += 256) {
        float m = pm[i * NSPLIT + 0], s = ps[i * NSPLIT + 0];
#pragma unroll
        for (int c = 1; c < NSPLIT; ++c) {
            float mo = pm[i * NSPLIT + c], so = ps[i * NSPLIT + c];
            float nm = fmaxf(m, mo);
            s = s * __expf(m - nm) + so * __expf(mo - nm);
            m = nm;
        }
        float lse = m + logf(s);
        bool valid = (idx[i] != -100);
        if (valid) {
            accn += diag[i] - lse;
            accd += 1.f;
        }
    }
#pragma unroll
    for (int m = 32; m >= 1; m >>= 1) {
        accn += __shfl_xor(accn, m);
        accd += __shfl_xor(accd, m);
    }
    __shared__ float an[4], ad[4];
    int wave = threadIdx.x >> 6, lane = threadIdx.x & 63;
    if (lane == 0) { an[wave] = accn; ad[wave] = accd; }
    __syncthreads();
    if (threadIdx.x == 0) {
        float n = an[0] + an[1] + an[2] + an[3];
        float d = ad[0] + ad[1] + ad[2] + ad[3];
        out[0] = -n / d;
    }
}

extern "C" void kernel_launch(void* const* d_in, const int* in_sizes, int n_in,
                              void* d_out, int out_size, void* d_ws, size_t ws_size,
                              hipStream_t stream) {
    const float* x      = (const float*)d_in[0];   // [8192][768]
    const float* labels = (const float*)d_in[1];   // [8192][768]
    const int*   lidx   = (const int*)d_in[2];     // [8192]
    const float* vm     = (const float*)d_in[3];   // [8192]
    const float* W1     = (const float*)d_in[4];   // [768][768]
    const float* b1     = (const float*)d_in[5];
    const float* ln_g   = (const float*)d_in[6];
    const float* ln_b   = (const float*)d_in[7];
    const float* Wd     = (const float*)d_in[8];
    const float* b_dec  = (const float*)d_in[9];
    float* out = (float*)d_out;

    const size_t NE = (size_t)ROWS * DPOS;       // 6291456
    const size_t NW = (size_t)DPOS * DPOS;       // 589824
    char* p = (char*)d_ws;
    __bf16* xb   = (__bf16*)p;            p += NE * 2;
    __bf16* labb = (__bf16*)p;            p += NE * 2;
    __bf16* W1b  = (__bf16*)p;            p += NW * 2;
    __bf16* Wdb  = (__bf16*)p;            p += NW * 2;
    __bf16* hb   = (__bf16*)p;            p += NE * 2;
    __bf16* hlnb = (__bf16*)p;            p += NE * 2;
    __bf16* embb = (__bf16*)p;            p += NE * 2;
    float*  pm   = (float*)p;             p += (size_t)ROWS * NSPLIT * 4;
    float*  ps   = (float*)p;             p += (size_t)ROWS * NSPLIT * 4;
    float*  diag = (float*)p;             p += (size_t)ROWS * 4;

    // convert fp32 -> bf16 (x+labels in one launch, W1+Wd in another)
    k_f2bf2<<<(2 * NE / 4) / 256, 256, 0, stream>>>(x, labels, xb, labb, (int)NE);
    k_f2bf2<<<(2 * NW / 4) / 256, 256, 0, stream>>>(W1, Wd, W1b, Wdb, (int)NW);

    // MFM block (LDS-staged GEMMs, 64x128 tiles -> 768 blocks)
    dim3 g1(ROWS / 64, DPOS / 128);
    k_gemm_ld<0><<<g1, 256, 0, stream>>>(xb, W1b, b1, hb);
    k_ln<<<ROWS, 256, 0, stream>>>(hb, ln_g, ln_b, hlnb);
    k_gemm_ld<1><<<g1, 256, 0, stream>>>(hlnb, Wdb, b_dec, embb);

    // contrastive loss
    dim3 g2(ROWS / BM, NSPLIT);
    k_lse_sb3<<<g2, 256, 0, stream>>>(embb, labb, vm, pm, ps);
    k_diag<<<ROWS / 4, 256, 0, stream>>>(embb, labb, diag);
    k_loss<<<1, 256, 0, stream>>>(pm, ps, diag, lidx, out);
}